// Round 1
// baseline (119.901 us; speedup 1.0000x reference)
//
#include <hip/hip_runtime.h>

typedef short bf16x8 __attribute__((ext_vector_type(8)));
typedef float f32x4  __attribute__((ext_vector_type(4)));

#define HN    32
#define CIN   64
#define KP    27
#define QB    64          // queries per block (old path)
#define CAPB  96          // entry slots per block (old path)
#define NTB   1024        // 16 waves (old path)
#define OSTR  65          // outacc stride (old path)

// new sparse path
#define EMAX  65536       // global entry capacity (~1.9x expected 34.5k)
#define OMAX  32768       // overflow list capacity
#define KG    7           // kernel-point groups (7 groups x 4 waves = 28 >= 27)
#define CBLK  896         // consumer blocks = KG * 128

#define INV_EXT 1.1547005383792517f   // 1/0.8660254
#define CUT2    3.4821f               // (1+0.8660254)^2 padded (extras get w=0)

__device__ __forceinline__ unsigned f2bf(float f){
    union{float fv;unsigned u;}v; v.fv=f;
    unsigned u=v.u;
    u += 0x7fffu + ((u>>16)&1u);      // RNE
    return u>>16;
}

// ---------------- old-path pack kernels (kept for small-ws fallback) -------
__global__ void pack_spts(const float* __restrict__ s, float4* __restrict__ o, int M){
    int i = blockIdx.x*256 + threadIdx.x;
    if (i < M) o[i] = make_float4(s[i*3+0], s[i*3+1], s[i*3+2], 0.f);
}

// Wt2[((k*8 + f)*64 + lane)*8 + j] = bf16( W[k][ks*32 + (lane>>4)*8 + j][ot*16 + (lane&15)] ), f = ot*2+ks
__global__ void pack_wt2(const float* __restrict__ W, unsigned short* __restrict__ Wt2){
    int tid = blockIdx.x*256 + threadIdx.x;
    if (tid >= KP*8*64) return;
    int lane = tid & 63;
    int f  = (tid>>6) & 7;
    int k  = tid >> 9;
    int ot = f>>1, ks = f&1, g = lane>>4;
    unsigned r[8];
#pragma unroll
    for (int j=0;j<8;++j)
        r[j] = f2bf(W[(size_t)k*4096 + (size_t)(ks*32 + g*8 + j)*64 + ot*16 + (lane&15)]);
    uint4 v; v.x=r[0]|(r[1]<<16); v.y=r[2]|(r[3]<<16); v.z=r[4]|(r[5]<<16); v.w=r[6]|(r[7]<<16);
    *(uint4*)&Wt2[(size_t)tid*8] = v;
}

__device__ __forceinline__ void loadB(const unsigned short* __restrict__ Wt2, int k, int lane,
                                      bf16x8 (&b)[8]){
    const unsigned short* base = Wt2 + ((size_t)(k*8)*64 + lane)*8;
#pragma unroll
    for (int f=0;f<8;++f) b[f] = *(const bf16x8*)(base + f*512);
}
__device__ __forceinline__ void loadB_w(const float* __restrict__ W, int k, int lane, int g,
                                        bf16x8 (&b)[8]){
#pragma unroll
    for (int f=0;f<8;++f){
        int ot=f>>1, ks=f&1;
        union{unsigned u[4]; bf16x8 v;} bb;
#pragma unroll
        for (int jj=0;jj<4;++jj){
            unsigned l0=f2bf(W[(size_t)k*4096 + (size_t)(ks*32+g*8+2*jj)*64   + ot*16+(lane&15)]);
            unsigned l1=f2bf(W[(size_t)k*4096 + (size_t)(ks*32+g*8+2*jj+1)*64 + ot*16+(lane&15)]);
            bb.u[jj]=l0|(l1<<16);
        }
        b[f]=bb.v;
    }
}

// ====================== NEW SPARSE PATH ====================================

// prep: sp4 pack + Wt2 pack + counter zero (one launch)
__global__ __launch_bounds__(256)
void kp_prep(const float* __restrict__ s, const float* __restrict__ W,
             float4* __restrict__ o, unsigned short* __restrict__ Wt2,
             int* __restrict__ ctrs, int M)
{
    int tid = blockIdx.x*256 + threadIdx.x;
    if (tid < 2) ctrs[tid] = 0;
    if (tid < M) o[tid] = make_float4(s[tid*3+0], s[tid*3+1], s[tid*3+2], 0.f);
    if (tid < KP*8*64){
        int lane = tid & 63;
        int f  = (tid>>6) & 7;
        int kk = tid >> 9;
        int ot = f>>1, ks = f&1, gg = lane>>4;
        unsigned r[8];
#pragma unroll
        for (int j=0;j<8;++j)
            r[j] = f2bf(W[(size_t)kk*4096 + (size_t)(ks*32 + gg*8 + j)*64 + ot*16 + (lane&15)]);
        uint4 v; v.x=r[0]|(r[1]<<16); v.y=r[2]|(r[3]<<16); v.z=r[4]|(r[5]<<16); v.w=r[6]|(r[7]<<16);
        *(uint4*)&Wt2[(size_t)tid*8] = v;
    }
}

// scan: test all N*H pairs, compact survivors into global list; also zero out.
// Hierarchical counter: LDS count per block -> ONE global atomic per block.
__global__ __launch_bounds__(256)
void kp_scan(const float* __restrict__ q_pts, const int* __restrict__ inds,
             const float4* __restrict__ sp4, float* __restrict__ out,
             int* __restrict__ ctrs, float4* __restrict__ meta,
             int* __restrict__ idxA, int* __restrict__ ovf, int N, int M)
{
    __shared__ int lcnt, gbase;
    const int t = threadIdx.x;
    if (t==0) lcnt = 0;
    __syncthreads();
    const int tid = blockIdx.x*256 + t;
    const int NP  = N*HN;
    // zero output (N*CIN floats = N*16 float4)
    {
        float4 z; z.x=0.f; z.y=0.f; z.z=0.f; z.w=0.f;
        for (int zi=tid; zi < N*(CIN/4); zi += gridDim.x*256)
            ((float4*)out)[zi] = z;
    }
    int ls=-1, ix=0, n=0; float px=0.f, py=0.f, pz=0.f;
    if (tid < NP){
        n  = tid >> 5;
        ix = inds[tid];
        if ((unsigned)ix < (unsigned)M){        // ix==M is shadow point
            float qx=q_pts[n*3+0], qy=q_pts[n*3+1], qz=q_pts[n*3+2];
            float4 s4 = sp4[ix];
            px=s4.x-qx; py=s4.y-qy; pz=s4.z-qz;
            if (px*px+py*py+pz*pz <= CUT2) ls = atomicAdd(&lcnt, 1);
        }
    }
    __syncthreads();
    if (t==0) gbase = (lcnt>0) ? atomicAdd(&ctrs[0], lcnt) : 0;
    __syncthreads();
    if (ls >= 0){
        int slot = gbase + ls;
        if (slot < EMAX){
            meta[slot] = make_float4(px, py, pz, __int_as_float(n));
            idxA[slot] = ix;
        } else {
            int o = atomicAdd(&ctrs[1], 1);
            if (o < OMAX) ovf[o] = tid;
        }
    }
}

// consumer: 4-wave blocks. block owns 4 kernel points (kgroup) x stripe of
// 16-entry tiles. Stage tile features once in LDS (XOR-swizzled bf16),
// each wave: one kernel point, ballot-skip if no active entry, MFMA,
// k-summed per wave, fire-and-forget global atomicAdd into out.
__global__ __launch_bounds__(256,4)
void kpconv_sparse(const float* __restrict__ x, const float* __restrict__ kpts,
                   const unsigned short* __restrict__ Wt2,
                   const float4* __restrict__ meta, const int* __restrict__ idxA,
                   const int* __restrict__ ctrs, const int* __restrict__ ovf,
                   const int* __restrict__ inds, const float* __restrict__ q_pts,
                   const float4* __restrict__ sp4, const float* __restrict__ W,
                   float* __restrict__ out, int N, int M)
{
    __shared__ unsigned short rows[16*CIN];     // 2 KB, XOR-swizzled bf16
    const int t    = threadIdx.x;
    const int lane = t & 63;
    const int wv   = t >> 6;                    // 4 waves
    const int g    = lane >> 4;
    const int r15  = lane & 15;
    const int kgroup  = blockIdx.x % KG;
    const int tile0   = blockIdx.x / KG;
    const int tstride = gridDim.x / KG;         // 128
    const int k    = kgroup*4 + wv;             // 0..27 (27 invalid)
    const bool hask = (k < KP);
    const int kl   = hask ? k : 0;

    int E = ctrs[0]; if (E > EMAX) E = EMAX;
    const int ntiles = (E + 15) >> 4;

    bf16x8 B0[8];
    loadB(Wt2, kl, lane, B0);
    const float kx=kpts[kl*3+0], ky=kpts[kl*3+1], kz=kpts[kl*3+2];

    for (int tile=tile0; tile<ntiles; tile+=tstride){
        const int base = tile*16;
        __syncthreads();                        // rows free for reuse
        // stage 16 feature rows (f32 -> bf16, swizzled); zero-pad past E
        for (int it=t; it<16*8; it+=256){
            int rl=it>>3, c8=it&7, e=base+rl;
            uint4 v; v.x=0u; v.y=0u; v.z=0u; v.w=0u;
            if (e < E){
                int ix = idxA[e];
                const float4* xr = (const float4*)(x + (size_t)ix*CIN);
                float4 f0=xr[c8*2], f1=xr[c8*2+1];
                v.x=f2bf(f0.x)|(f2bf(f0.y)<<16); v.y=f2bf(f0.z)|(f2bf(f0.w)<<16);
                v.z=f2bf(f1.x)|(f2bf(f1.y)<<16); v.w=f2bf(f1.z)|(f2bf(f1.w)<<16);
            }
            int ba = rl*128 + ((c8*16)^((rl&7)<<4));
            *(uint4*)((char*)rows+ba) = v;
        }
        // per-wave weights for this kernel point (overlaps staging latency)
        float w0[4]; int qq[4];
#pragma unroll
        for (int r=0;r<4;++r){
            int em = base + g*4 + r;
            float wr=0.f; int qv=0;
            if (hask && em < E){
                float4 mv = meta[em];
                qv = __float_as_int(mv.w);
                float dx=mv.x-kx, dy=mv.y-ky, dz=mv.z-kz;
                wr = fmaxf(1.f - sqrtf(dx*dx+dy*dy+dz*dz)*INV_EXT, 0.f);
            }
            w0[r]=wr; qq[r]=qv;
        }
        __syncthreads();                        // rows staged
        if (hask && __any(w0[0]>0.f || w0[1]>0.f || w0[2]>0.f || w0[3]>0.f)){
            const char* rb = (const char*)rows;
            bf16x8 a0 = *(const bf16x8*)(rb + r15*128 + (( g*16)   ^((r15&7)<<4)));
            bf16x8 a1 = *(const bf16x8*)(rb + r15*128 + ((64+g*16) ^((r15&7)<<4)));
#pragma unroll
            for (int ot=0;ot<4;++ot){
                f32x4 c={0.f,0.f,0.f,0.f};
                c=__builtin_amdgcn_mfma_f32_16x16x32_bf16(a0,B0[2*ot  ],c,0,0,0);
                c=__builtin_amdgcn_mfma_f32_16x16x32_bf16(a1,B0[2*ot+1],c,0,0,0);
#pragma unroll
                for (int r=0;r<4;++r){
                    float val = w0[r]*c[r];
                    if (val!=0.f) atomicAdd(out + (size_t)qq[r]*CIN + ot*16 + r15, val);
                }
            }
        }
    }

    // overflow slow path (exact; statistically never taken)
    int ovn = ctrs[1]; if (ovn > OMAX) ovn = OMAX;
    if (ovn > 0){
        int Wid = blockIdx.x*4 + wv, nWv = gridDim.x*4;
        for (int o=Wid; o<ovn; o+=nWv){
            int p = ovf[o]; int n = p >> 5;
            int ix = inds[p];
            float qx=q_pts[n*3+0], qy=q_pts[n*3+1], qz=q_pts[n*3+2];
            float4 s4 = sp4[ix];
            float px=s4.x-qx, py=s4.y-qy, pz=s4.z-qz;
            for (int kk=0; kk<KP; ++kk){
                float dx=px-kpts[kk*3+0], dy=py-kpts[kk*3+1], dz=pz-kpts[kk*3+2];
                float w = fmaxf(1.f - sqrtf(dx*dx+dy*dy+dz*dz)*INV_EXT, 0.f);
                if (w > 0.f){
                    float a=0.f;
                    for (int c=0;c<CIN;++c)
                        a += x[(size_t)ix*CIN+c]*W[(size_t)kk*CIN*CIN + (size_t)c*CIN + lane];
                    atomicAdd(out + (size_t)n*CIN + lane, w*a);
                }
            }
        }
    }
}

// ====================== OLD PATH (fallback) ================================

__global__ __launch_bounds__(NTB)
void kpconv6(const float* __restrict__ q_pts, const float* __restrict__ s_pts,
             const int* __restrict__ inds, const float* __restrict__ x,
             const float* __restrict__ W, const float* __restrict__ kpts,
             const float4* __restrict__ sp4, const unsigned short* __restrict__ Wt2,
             int use_ws, float* __restrict__ out, int N, int M)
{
    __shared__ float qls[QB*3];
    __shared__ float posx[CAPB], posy[CAPB], posz[CAPB];
    __shared__ int   eqb[CAPB], eidxb[CAPB];
    __shared__ unsigned short rows[CAPB*CIN];
    __shared__ float outacc[QB*OSTR];
    __shared__ int   cnt;

    const int t    = threadIdx.x;
    const int lane = t & 63;
    const int wv   = t >> 6;
    const int g    = lane >> 4;
    const int r15  = lane & 15;
    const int nq0  = blockIdx.x * QB;

    const int k0 = wv, k1 = wv + 16;
    const bool has2 = (k1 < KP);

    bf16x8 B0[8], B1[8];
    if (use_ws){
        loadB(Wt2, k0, lane, B0);
        loadB(Wt2, has2 ? k1 : k0, lane, B1);
    } else {
        loadB_w(W, k0, lane, g, B0);
        loadB_w(W, has2 ? k1 : k0, lane, g, B1);
    }
    const float k0x=kpts[k0*3+0], k0y=kpts[k0*3+1], k0z=kpts[k0*3+2];
    float k1x=0.f,k1y=0.f,k1z=0.f;
    if (has2){ k1x=kpts[k1*3+0]; k1y=kpts[k1*3+1]; k1z=kpts[k1*3+2]; }

    for (int j=t; j<QB*OSTR; j+=NTB) outacc[j]=0.f;
    for (int j=t; j<QB*3;   j+=NTB){ int gi=nq0*3+j; qls[j]=(gi<N*3)? q_pts[gi]:0.f; }
    if (t==0) cnt=0;
    __syncthreads();

    auto process = [&](int cc){
        if (cc<=0) return;
        const int ntile=(cc+15)>>4, nrow=ntile*16;
        for (int j=cc+t; j<nrow; j+=NTB){ posx[j]=1e9f; posy[j]=1e9f; posz[j]=1e9f; eqb[j]=0; }
        for (int it=t; it<nrow*8; it+=NTB){
            int e=it>>3, c8=it&7;
            uint4 v; v.x=0u; v.y=0u; v.z=0u; v.w=0u;
            if (e<cc){
                const float4* xr=(const float4*)(x+(size_t)eidxb[e]*CIN);
                float4 f0=xr[c8*2], f1=xr[c8*2+1];
                v.x=f2bf(f0.x)|(f2bf(f0.y)<<16); v.y=f2bf(f0.z)|(f2bf(f0.w)<<16);
                v.z=f2bf(f1.x)|(f2bf(f1.y)<<16); v.w=f2bf(f1.z)|(f2bf(f1.w)<<16);
            }
            int ba=e*128+((c8*16)^((e&7)<<4));
            *(uint4*)((char*)rows+ba)=v;
        }
        __syncthreads();
        for (int tile=0; tile<ntile; ++tile){
            const char* rb=(const char*)rows;
            int row=tile*16+r15;
            bf16x8 a0=*(const bf16x8*)(rb+row*128+((g*16)    ^((row&7)<<4)));
            bf16x8 a1=*(const bf16x8*)(rb+row*128+((64+g*16) ^((row&7)<<4)));
            int rbase=tile*16+g*4;
            float w0[4], w1[4]; int qq[4];
#pragma unroll
            for (int r=0;r<4;++r){
                float sx=posx[rbase+r], sy=posy[rbase+r], sz=posz[rbase+r];
                qq[r]=eqb[rbase+r];
                float dx=sx-k0x, dy=sy-k0y, dz=sz-k0z;
                w0[r]=fmaxf(1.f-sqrtf(dx*dx+dy*dy+dz*dz)*INV_EXT,0.f);
                float ex=sx-k1x, ey=sy-k1y, ez=sz-k1z;
                float w1r=fmaxf(1.f-sqrtf(ex*ex+ey*ey+ez*ez)*INV_EXT,0.f);
                w1[r]=has2? w1r : 0.f;
            }
#pragma unroll
            for (int ot=0;ot<4;++ot){
                f32x4 c={0.f,0.f,0.f,0.f};
                c=__builtin_amdgcn_mfma_f32_16x16x32_bf16(a0,B0[2*ot],c,0,0,0);
                c=__builtin_amdgcn_mfma_f32_16x16x32_bf16(a1,B0[2*ot+1],c,0,0,0);
                f32x4 d={0.f,0.f,0.f,0.f};
                if (has2){
                    d=__builtin_amdgcn_mfma_f32_16x16x32_bf16(a0,B1[2*ot],d,0,0,0);
                    d=__builtin_amdgcn_mfma_f32_16x16x32_bf16(a1,B1[2*ot+1],d,0,0,0);
                }
#pragma unroll
                for (int r=0;r<4;++r){
                    float val=w0[r]*c[r]+w1[r]*d[r];
                    if (val!=0.f) atomicAdd(&outacc[qq[r]*OSTR+ot*16+r15], val);
                }
            }
        }
        __syncthreads();
    };

    for (int it=t; it<QB*HN; it+=NTB){
        int q=it>>5, h=it&31, n=nq0+q;
        bool inr=false; int idx=0; float px=0.f,py=0.f,pz=0.f;
        if (n<N){
            idx=inds[(size_t)n*HN+h];
            if ((unsigned)idx<(unsigned)M){
                float sx,sy,sz;
                if (use_ws){ float4 s4=sp4[idx]; sx=s4.x; sy=s4.y; sz=s4.z; }
                else { sx=s_pts[idx*3]; sy=s_pts[idx*3+1]; sz=s_pts[idx*3+2]; }
                px=sx-qls[q*3]; py=sy-qls[q*3+1]; pz=sz-qls[q*3+2];
                inr=(px*px+py*py+pz*pz)<=CUT2;
            }
        }
        if (inr){
            int sl=atomicAdd(&cnt,1);
            if (sl<CAPB){ eqb[sl]=q; eidxb[sl]=idx; posx[sl]=px; posy[sl]=py; posz[sl]=pz; }
        }
    }
    __syncthreads();
    const int total=cnt;

    if (total<=CAPB){
        process(total);
    } else {
        for (int w=0; w<(QB*HN)/64; ++w){
            __syncthreads();
            if (t==0) cnt=0;
            __syncthreads();
            if (t<64){
                int pair=w*64+t;
                int q=pair>>5, h=pair&31, n=nq0+q;
                if (n<N){
                    int idx=inds[(size_t)n*HN+h];
                    if ((unsigned)idx<(unsigned)M){
                        float sx,sy,sz;
                        if (use_ws){ float4 s4=sp4[idx]; sx=s4.x; sy=s4.y; sz=s4.z; }
                        else { sx=s_pts[idx*3]; sy=s_pts[idx*3+1]; sz=s_pts[idx*3+2]; }
                        float px=sx-qls[q*3], py=sy-qls[q*3+1], pz=sz-qls[q*3+2];
                        if (px*px+py*py+pz*pz<=CUT2){
                            int sl=atomicAdd(&cnt,1);
                            eqb[sl]=q; eidxb[sl]=idx; posx[sl]=px; posy[sl]=py; posz[sl]=pz;
                        }
                    }
                }
            }
            __syncthreads();
            process(cnt);
        }
    }
    __syncthreads();

    for (int j=t; j<QB*CIN; j+=NTB){
        int q=j>>6, o=j&63, n=nq0+q;
        if (n<N) out[(size_t)n*CIN+o]=outacc[q*OSTR+o];
    }
}

extern "C" void kernel_launch(void* const* d_in, const int* in_sizes, int n_in,
                              void* d_out, int out_size, void* d_ws, size_t ws_size,
                              hipStream_t stream)
{
    const float* q_pts=(const float*)d_in[0];
    const float* s_pts=(const float*)d_in[1];
    const int*   inds =(const int*)d_in[2];
    const float* x    =(const float*)d_in[3];
    const float* W    =(const float*)d_in[4];
    const float* kpts =(const float*)d_in[5];
    float* outp=(float*)d_out;
    int N=in_sizes[0]/3;
    int M=in_sizes[1]/3;

    char* wsb=(char*)d_ws;
    float4* sp4=(float4*)wsb;
    unsigned short* Wt2=(unsigned short*)(wsb + (size_t)M*16);

    const size_t WT2B = (size_t)KP*8*64*8*2;            // 221184
    size_t offC = (size_t)M*16 + WT2B;                  // 16/256-aligned
    size_t newNeed = offC + 256 + (size_t)EMAX*16 + (size_t)EMAX*4 + (size_t)OMAX*4;

    if (ws_size >= newNeed){
        int*    ctrs =(int*)   (wsb + offC);
        float4* meta =(float4*)(wsb + offC + 256);
        int*    idxA =(int*)   (wsb + offC + 256 + (size_t)EMAX*16);
        int*    ovf  =(int*)   (wsb + offC + 256 + (size_t)EMAX*16 + (size_t)EMAX*4);

        int prepN = (M > KP*8*64) ? M : KP*8*64;
        hipLaunchKernelGGL(kp_prep, dim3((prepN+255)/256), dim3(256), 0, stream,
                           s_pts, W, sp4, Wt2, ctrs, M);
        hipLaunchKernelGGL(kp_scan, dim3((N*HN+255)/256), dim3(256), 0, stream,
                           q_pts, inds, sp4, outp, ctrs, meta, idxA, ovf, N, M);
        hipLaunchKernelGGL(kpconv_sparse, dim3(CBLK), dim3(256), 0, stream,
                           x, kpts, Wt2, meta, idxA, ctrs, ovf, inds, q_pts, sp4, W,
                           outp, N, M);
        return;
    }

    // fallback: previous best single-kernel path
    size_t need = (size_t)M*16 + WT2B;
    int use_ws = (ws_size >= need) ? 1 : 0;
    if (use_ws){
        hipLaunchKernelGGL(pack_spts, dim3((M+255)/256), dim3(256), 0, stream, s_pts, sp4, M);
        hipLaunchKernelGGL(pack_wt2, dim3((KP*8*64+255)/256), dim3(256), 0, stream, W, Wt2);
    }
    int nblocks = (N + QB - 1) / QB;
    hipLaunchKernelGGL(kpconv6, dim3(nblocks), dim3(NTB), 0, stream,
                       q_pts, s_pts, inds, x, W, kpts, sp4, Wt2, use_ws, outp, N, M);
}

// Round 2
// 42.645 us; speedup vs baseline: 2.8116x; 2.8116x over previous
//
#include <hip/hip_runtime.h>

typedef short bf16x8 __attribute__((ext_vector_type(8)));
typedef float f32x4  __attribute__((ext_vector_type(4)));

#define HN    32
#define CIN   64
#define KP    27
#define QB    64          // queries per block (old fallback path)
#define CAPB  96          // entry slots per block (old fallback path)
#define NTB   1024        // 16 waves (old fallback path)
#define OSTR  65          // outacc stride (old fallback path)

// sparse path
#define EMAX  65536       // global entry capacity (~1.9x expected 34.5k)
#define OMAX  32768       // overflow list capacity
#define PB    4096        // pairs per scan block
#define SCAP  384         // LDS survivor buffer per scan block (exp ~107, +19 sigma)
#define TPB   64          // entries per consumer tile/block

#define INV_EXT 1.1547005383792517f   // 1/0.8660254
#define CUT2    3.4821f               // (1+0.8660254)^2 padded (extras get w=0)

__device__ __forceinline__ unsigned f2bf(float f){
    union{float fv;unsigned u;}v; v.fv=f;
    unsigned u=v.u;
    u += 0x7fffu + ((u>>16)&1u);      // RNE
    return u>>16;
}

// ---------------- old-path pack kernels (kept for small-ws fallback) -------
__global__ void pack_spts(const float* __restrict__ s, float4* __restrict__ o, int M){
    int i = blockIdx.x*256 + threadIdx.x;
    if (i < M) o[i] = make_float4(s[i*3+0], s[i*3+1], s[i*3+2], 0.f);
}

// Wt2[((k*8 + f)*64 + lane)*8 + j] = bf16( W[k][ks*32 + (lane>>4)*8 + j][ot*16 + (lane&15)] ), f = ot*2+ks
__global__ void pack_wt2(const float* __restrict__ W, unsigned short* __restrict__ Wt2){
    int tid = blockIdx.x*256 + threadIdx.x;
    if (tid >= KP*8*64) return;
    int lane = tid & 63;
    int f  = (tid>>6) & 7;
    int k  = tid >> 9;
    int ot = f>>1, ks = f&1, g = lane>>4;
    unsigned r[8];
#pragma unroll
    for (int j=0;j<8;++j)
        r[j] = f2bf(W[(size_t)k*4096 + (size_t)(ks*32 + g*8 + j)*64 + ot*16 + (lane&15)]);
    uint4 v; v.x=r[0]|(r[1]<<16); v.y=r[2]|(r[3]<<16); v.z=r[4]|(r[5]<<16); v.w=r[6]|(r[7]<<16);
    *(uint4*)&Wt2[(size_t)tid*8] = v;
}

__device__ __forceinline__ void loadB(const unsigned short* __restrict__ Wt2, int k, int lane,
                                      bf16x8 (&b)[8]){
    const unsigned short* base = Wt2 + ((size_t)(k*8)*64 + lane)*8;
#pragma unroll
    for (int f=0;f<8;++f) b[f] = *(const bf16x8*)(base + f*512);
}
__device__ __forceinline__ bf16x8 ldBf(const unsigned short* __restrict__ Wt2, int k, int f, int lane){
    return *(const bf16x8*)(Wt2 + ((size_t)(k*8 + f)*64 + lane)*8);
}
__device__ __forceinline__ void loadB_w(const float* __restrict__ W, int k, int lane, int g,
                                        bf16x8 (&b)[8]){
#pragma unroll
    for (int f=0;f<8;++f){
        int ot=f>>1, ks=f&1;
        union{unsigned u[4]; bf16x8 v;} bb;
#pragma unroll
        for (int jj=0;jj<4;++jj){
            unsigned l0=f2bf(W[(size_t)k*4096 + (size_t)(ks*32+g*8+2*jj)*64   + ot*16+(lane&15)]);
            unsigned l1=f2bf(W[(size_t)k*4096 + (size_t)(ks*32+g*8+2*jj+1)*64 + ot*16+(lane&15)]);
            bb.u[jj]=l0|(l1<<16);
        }
        b[f]=bb.v;
    }
}

// ====================== SPARSE PATH ========================================

// prep: sp4 pack + Wt2 pack + counter zero (one launch)
__global__ __launch_bounds__(256)
void kp_prep(const float* __restrict__ s, const float* __restrict__ W,
             float4* __restrict__ o, unsigned short* __restrict__ Wt2,
             int* __restrict__ ctrs, int M)
{
    int tid = blockIdx.x*256 + threadIdx.x;
    if (tid < 2) ctrs[tid] = 0;
    if (tid < M) o[tid] = make_float4(s[tid*3+0], s[tid*3+1], s[tid*3+2], 0.f);
    if (tid < KP*8*64){
        int lane = tid & 63;
        int f  = (tid>>6) & 7;
        int kk = tid >> 9;
        int ot = f>>1, ks = f&1, gg = lane>>4;
        unsigned r[8];
#pragma unroll
        for (int j=0;j<8;++j)
            r[j] = f2bf(W[(size_t)kk*4096 + (size_t)(ks*32 + gg*8 + j)*64 + ot*16 + (lane&15)]);
        uint4 v; v.x=r[0]|(r[1]<<16); v.y=r[2]|(r[3]<<16); v.z=r[4]|(r[5]<<16); v.w=r[6]|(r[7]<<16);
        *(uint4*)&Wt2[(size_t)tid*8] = v;
    }
}

// scan v2: 4096 pairs/block, survivors buffered in LDS, ONE global counter
// atomic per block (313 total vs 5000), coalesced write-out. Also zeroes out.
__global__ __launch_bounds__(256)
void kp_scan2(const float* __restrict__ q_pts, const int* __restrict__ inds,
              const float4* __restrict__ sp4, float* __restrict__ out,
              int* __restrict__ ctrs, float4* __restrict__ meta,
              int* __restrict__ idxA, int* __restrict__ ovf, int N, int M)
{
    __shared__ float bx[SCAP], by[SCAP], bz[SCAP];
    __shared__ int   bix[SCAP], bp[SCAP];
    __shared__ int   lcnt, gbase;
    const int t = threadIdx.x;
    if (t==0) lcnt = 0;
    // zero output (N*CIN floats = N*16 float4), grid-strided
    for (int zi = blockIdx.x*256 + t; zi < N*(CIN/4); zi += gridDim.x*256)
        ((float4*)out)[zi] = make_float4(0.f,0.f,0.f,0.f);
    __syncthreads();

    const int NP = N*HN;
    const int p0 = blockIdx.x * PB;
#pragma unroll 2
    for (int j=0; j<PB/256; ++j){
        int pair = p0 + j*256 + t;
        if (pair < NP){
            int ix = inds[pair];
            if ((unsigned)ix < (unsigned)M){        // ix==M is shadow point
                int n = pair >> 5;
                float qx=q_pts[n*3+0], qy=q_pts[n*3+1], qz=q_pts[n*3+2];
                float4 s4 = sp4[ix];
                float px=s4.x-qx, py=s4.y-qy, pz=s4.z-qz;
                if (px*px+py*py+pz*pz <= CUT2){
                    int sl = atomicAdd(&lcnt, 1);
                    if (sl < SCAP){ bx[sl]=px; by[sl]=py; bz[sl]=pz; bix[sl]=ix; bp[sl]=pair; }
                    else { int o = atomicAdd(&ctrs[1],1); if (o<OMAX) ovf[o]=pair; }
                }
            }
        }
    }
    __syncthreads();
    int cnt = lcnt; if (cnt > SCAP) cnt = SCAP;
    if (t==0) gbase = (cnt>0) ? atomicAdd(&ctrs[0], cnt) : 0;
    __syncthreads();
    for (int s=t; s<cnt; s+=256){
        int slot = gbase + s;
        if (slot < EMAX){
            meta[slot] = make_float4(bx[s], by[s], bz[s], __int_as_float(bp[s]>>5));
            idxA[slot] = bix[s];
        } else {
            int o = atomicAdd(&ctrs[1],1);
            if (o < OMAX) ovf[o] = bp[s];
        }
    }
}

// consumer v2: one block per 64-entry tile (staged ONCE). 4 waves; wave wv owns
// output columns [wv*16, wv*16+16) and loops ALL 27 kernel points with
// double-buffered B frags from L2-hot Wt2. Per-block LDS w[27][64] table
// computed once. Register acc across k -> no cross-wave overlap -> one
// coalesced atomicAdd per output element per tile.
__global__ __launch_bounds__(256,4)
void kpconv_sp2(const float* __restrict__ x, const float* __restrict__ kpts,
                const unsigned short* __restrict__ Wt2,
                const float4* __restrict__ meta, const int* __restrict__ idxA,
                const int* __restrict__ ctrs, const int* __restrict__ ovf,
                const int* __restrict__ inds, const float* __restrict__ q_pts,
                const float4* __restrict__ sp4, const float* __restrict__ W,
                float* __restrict__ out, int N, int M)
{
    __shared__ unsigned short rows[TPB*CIN];              // 8 KB, XOR-swizzled bf16
    __shared__ __align__(16) float wlds[KP*TPB];          // 6.75 KB
    __shared__ float psx[TPB], psy[TPB], psz[TPB];
    __shared__ __align__(16) int qls[TPB];

    const int t    = threadIdx.x;
    const int lane = t & 63;
    const int wv   = t >> 6;        // wave owns ot = wv
    const int g    = lane >> 4;
    const int r15  = lane & 15;

    int E = ctrs[0]; if (E > EMAX) E = EMAX;
    const int ntiles = (E + TPB - 1) / TPB;
    const int tile = blockIdx.x;

    if (tile < ntiles){
        const int base = tile*TPB;
        // meta -> LDS (pos + q); pad rows get far-away pos -> w==0
        if (t < TPB){
            int e = base + t;
            float4 mv = (e < E) ? meta[e]
                                : make_float4(1e9f,1e9f,1e9f,__int_as_float(0));
            psx[t]=mv.x; psy[t]=mv.y; psz[t]=mv.z; qls[t]=__float_as_int(mv.w);
        }
        // stage 64 feature rows (f32 -> bf16, swizzled); zero-pad past E
        for (int it=t; it<TPB*8; it+=256){
            int rl=it>>3, c8=it&7, e=base+rl;
            uint4 v; v.x=0u; v.y=0u; v.z=0u; v.w=0u;
            if (e < E){
                int ix = idxA[e];
                const float4* xr = (const float4*)(x + (size_t)ix*CIN);
                float4 f0=xr[c8*2], f1=xr[c8*2+1];
                v.x=f2bf(f0.x)|(f2bf(f0.y)<<16); v.y=f2bf(f0.z)|(f2bf(f0.w)<<16);
                v.z=f2bf(f1.x)|(f2bf(f1.y)<<16); v.w=f2bf(f1.z)|(f2bf(f1.w)<<16);
            }
            int ba = rl*128 + ((c8*16)^((rl&7)<<4));
            *(uint4*)((char*)rows+ba) = v;
        }
        __syncthreads();
        // w table: w[k][row], 27*64 = 1728 values over 256 threads
        for (int i=t; i<KP*TPB; i+=256){
            int k = i>>6, row = i&63;
            float dx=psx[row]-kpts[k*3+0];
            float dy=psy[row]-kpts[k*3+1];
            float dz=psz[row]-kpts[k*3+2];
            wlds[i] = fmaxf(1.f - sqrtf(dx*dx+dy*dy+dz*dz)*INV_EXT, 0.f);
        }
        __syncthreads();

        // A fragments in registers, once per tile
        const char* rb = (const char*)rows;
        bf16x8 A0[4], A1[4];
#pragma unroll
        for (int rt=0; rt<4; ++rt){
            int row = rt*16 + r15;
            A0[rt] = *(const bf16x8*)(rb + row*128 + (( g*16)    ^((row&7)<<4)));
            A1[rt] = *(const bf16x8*)(rb + row*128 + ((64+g*16)  ^((row&7)<<4)));
        }
        f32x4 acc[4];
#pragma unroll
        for (int rt=0; rt<4; ++rt){ acc[rt][0]=0.f; acc[rt][1]=0.f; acc[rt][2]=0.f; acc[rt][3]=0.f; }

        const int f0 = wv*2, f1 = wv*2+1;
        bf16x8 Bc0 = ldBf(Wt2, 0, f0, lane);
        bf16x8 Bc1 = ldBf(Wt2, 0, f1, lane);
#pragma unroll 1
        for (int k=0; k<KP; ++k){
            int kn = (k+1 < KP) ? (k+1) : k;
            bf16x8 Bn0 = ldBf(Wt2, kn, f0, lane);
            bf16x8 Bn1 = ldBf(Wt2, kn, f1, lane);
            const float* wk = &wlds[k*TPB];
#pragma unroll
            for (int rt=0; rt<4; ++rt){
                f32x4 w4 = *(const f32x4*)(wk + rt*16 + g*4);
                bool act = (w4[0]>0.f)|(w4[1]>0.f)|(w4[2]>0.f)|(w4[3]>0.f);
                if (__any(act)){
                    f32x4 c; c[0]=0.f; c[1]=0.f; c[2]=0.f; c[3]=0.f;
                    c = __builtin_amdgcn_mfma_f32_16x16x32_bf16(A0[rt], Bc0, c, 0,0,0);
                    c = __builtin_amdgcn_mfma_f32_16x16x32_bf16(A1[rt], Bc1, c, 0,0,0);
                    acc[rt][0] += w4[0]*c[0];
                    acc[rt][1] += w4[1]*c[1];
                    acc[rt][2] += w4[2]*c[2];
                    acc[rt][3] += w4[3]*c[3];
                }
            }
            Bc0 = Bn0; Bc1 = Bn1;
        }
        // flush: wave owns cols [wv*16, wv*16+16) -> no cross-wave overlap
#pragma unroll
        for (int rt=0; rt<4; ++rt){
            int4 q4 = *(const int4*)&qls[rt*16 + g*4];
#pragma unroll
            for (int rr=0; rr<4; ++rr){
                float val = acc[rt][rr];
                int qv = (rr==0)? q4.x : (rr==1)? q4.y : (rr==2)? q4.z : q4.w;
                if (val != 0.f)
                    atomicAdd(out + (size_t)qv*CIN + wv*16 + r15, val);
            }
        }
    }

    // overflow slow path (exact; statistically never taken)
    int ovn = ctrs[1]; if (ovn > OMAX) ovn = OMAX;
    if (ovn > 0){
        int Wid = blockIdx.x*4 + wv, nWv = gridDim.x*4;
        for (int o=Wid; o<ovn; o+=nWv){
            int p = ovf[o]; int n = p >> 5;
            int ix = inds[p];
            float qx=q_pts[n*3+0], qy=q_pts[n*3+1], qz=q_pts[n*3+2];
            float4 s4 = sp4[ix];
            float px=s4.x-qx, py=s4.y-qy, pz=s4.z-qz;
            for (int kk=0; kk<KP; ++kk){
                float dx=px-kpts[kk*3+0], dy=py-kpts[kk*3+1], dz=pz-kpts[kk*3+2];
                float w = fmaxf(1.f - sqrtf(dx*dx+dy*dy+dz*dz)*INV_EXT, 0.f);
                if (w > 0.f){
                    float a=0.f;
                    for (int c=0;c<CIN;++c)
                        a += x[(size_t)ix*CIN+c]*W[(size_t)kk*CIN*CIN + (size_t)c*CIN + lane];
                    atomicAdd(out + (size_t)n*CIN + lane, w*a);
                }
            }
        }
    }
}

// ====================== OLD PATH (fallback) ================================

__global__ __launch_bounds__(NTB)
void kpconv6(const float* __restrict__ q_pts, const float* __restrict__ s_pts,
             const int* __restrict__ inds, const float* __restrict__ x,
             const float* __restrict__ W, const float* __restrict__ kpts,
             const float4* __restrict__ sp4, const unsigned short* __restrict__ Wt2,
             int use_ws, float* __restrict__ out, int N, int M)
{
    __shared__ float qls[QB*3];
    __shared__ float posx[CAPB], posy[CAPB], posz[CAPB];
    __shared__ int   eqb[CAPB], eidxb[CAPB];
    __shared__ unsigned short rows[CAPB*CIN];
    __shared__ float outacc[QB*OSTR];
    __shared__ int   cnt;

    const int t    = threadIdx.x;
    const int lane = t & 63;
    const int wv   = t >> 6;
    const int g    = lane >> 4;
    const int r15  = lane & 15;
    const int nq0  = blockIdx.x * QB;

    const int k0 = wv, k1 = wv + 16;
    const bool has2 = (k1 < KP);

    bf16x8 B0[8], B1[8];
    if (use_ws){
        loadB(Wt2, k0, lane, B0);
        loadB(Wt2, has2 ? k1 : k0, lane, B1);
    } else {
        loadB_w(W, k0, lane, g, B0);
        loadB_w(W, has2 ? k1 : k0, lane, g, B1);
    }
    const float k0x=kpts[k0*3+0], k0y=kpts[k0*3+1], k0z=kpts[k0*3+2];
    float k1x=0.f,k1y=0.f,k1z=0.f;
    if (has2){ k1x=kpts[k1*3+0]; k1y=kpts[k1*3+1]; k1z=kpts[k1*3+2]; }

    for (int j=t; j<QB*OSTR; j+=NTB) outacc[j]=0.f;
    for (int j=t; j<QB*3;   j+=NTB){ int gi=nq0*3+j; qls[j]=(gi<N*3)? q_pts[gi]:0.f; }
    if (t==0) cnt=0;
    __syncthreads();

    auto process = [&](int cc){
        if (cc<=0) return;
        const int ntile=(cc+15)>>4, nrow=ntile*16;
        for (int j=cc+t; j<nrow; j+=NTB){ posx[j]=1e9f; posy[j]=1e9f; posz[j]=1e9f; eqb[j]=0; }
        for (int it=t; it<nrow*8; it+=NTB){
            int e=it>>3, c8=it&7;
            uint4 v; v.x=0u; v.y=0u; v.z=0u; v.w=0u;
            if (e<cc){
                const float4* xr=(const float4*)(x+(size_t)eidxb[e]*CIN);
                float4 f0=xr[c8*2], f1=xr[c8*2+1];
                v.x=f2bf(f0.x)|(f2bf(f0.y)<<16); v.y=f2bf(f0.z)|(f2bf(f0.w)<<16);
                v.z=f2bf(f1.x)|(f2bf(f1.y)<<16); v.w=f2bf(f1.z)|(f2bf(f1.w)<<16);
            }
            int ba=e*128+((c8*16)^((e&7)<<4));
            *(uint4*)((char*)rows+ba)=v;
        }
        __syncthreads();
        for (int tile=0; tile<ntile; ++tile){
            const char* rb=(const char*)rows;
            int row=tile*16+r15;
            bf16x8 a0=*(const bf16x8*)(rb+row*128+((g*16)    ^((row&7)<<4)));
            bf16x8 a1=*(const bf16x8*)(rb+row*128+((64+g*16) ^((row&7)<<4)));
            int rbase=tile*16+g*4;
            float w0[4], w1[4]; int qq[4];
#pragma unroll
            for (int r=0;r<4;++r){
                float sx=posx[rbase+r], sy=posy[rbase+r], sz=posz[rbase+r];
                qq[r]=eqb[rbase+r];
                float dx=sx-k0x, dy=sy-k0y, dz=sz-k0z;
                w0[r]=fmaxf(1.f-sqrtf(dx*dx+dy*dy+dz*dz)*INV_EXT,0.f);
                float ex=sx-k1x, ey=sy-k1y, ez=sz-k1z;
                float w1r=fmaxf(1.f-sqrtf(ex*ex+ey*ey+ez*ez)*INV_EXT,0.f);
                w1[r]=has2? w1r : 0.f;
            }
#pragma unroll
            for (int ot=0;ot<4;++ot){
                f32x4 c={0.f,0.f,0.f,0.f};
                c=__builtin_amdgcn_mfma_f32_16x16x32_bf16(a0,B0[2*ot],c,0,0,0);
                c=__builtin_amdgcn_mfma_f32_16x16x32_bf16(a1,B0[2*ot+1],c,0,0,0);
                f32x4 d={0.f,0.f,0.f,0.f};
                if (has2){
                    d=__builtin_amdgcn_mfma_f32_16x16x32_bf16(a0,B1[2*ot],d,0,0,0);
                    d=__builtin_amdgcn_mfma_f32_16x16x32_bf16(a1,B1[2*ot+1],d,0,0,0);
                }
#pragma unroll
                for (int r=0;r<4;++r){
                    float val=w0[r]*c[r]+w1[r]*d[r];
                    if (val!=0.f) atomicAdd(&outacc[qq[r]*OSTR+ot*16+r15], val);
                }
            }
        }
        __syncthreads();
    };

    for (int it=t; it<QB*HN; it+=NTB){
        int q=it>>5, h=it&31, n=nq0+q;
        bool inr=false; int idx=0; float px=0.f,py=0.f,pz=0.f;
        if (n<N){
            idx=inds[(size_t)n*HN+h];
            if ((unsigned)idx<(unsigned)M){
                float sx,sy,sz;
                if (use_ws){ float4 s4=sp4[idx]; sx=s4.x; sy=s4.y; sz=s4.z; }
                else { sx=s_pts[idx*3]; sy=s_pts[idx*3+1]; sz=s_pts[idx*3+2]; }
                px=sx-qls[q*3]; py=sy-qls[q*3+1]; pz=sz-qls[q*3+2];
                inr=(px*px+py*py+pz*pz)<=CUT2;
            }
        }
        if (inr){
            int sl=atomicAdd(&cnt,1);
            if (sl<CAPB){ eqb[sl]=q; eidxb[sl]=idx; posx[sl]=px; posy[sl]=py; posz[sl]=pz; }
        }
    }
    __syncthreads();
    const int total=cnt;

    if (total<=CAPB){
        process(total);
    } else {
        for (int w=0; w<(QB*HN)/64; ++w){
            __syncthreads();
            if (t==0) cnt=0;
            __syncthreads();
            if (t<64){
                int pair=w*64+t;
                int q=pair>>5, h=pair&31, n=nq0+q;
                if (n<N){
                    int idx=inds[(size_t)n*HN+h];
                    if ((unsigned)idx<(unsigned)M){
                        float sx,sy,sz;
                        if (use_ws){ float4 s4=sp4[idx]; sx=s4.x; sy=s4.y; sz=s4.z; }
                        else { sx=s_pts[idx*3]; sy=s_pts[idx*3+1]; sz=s_pts[idx*3+2]; }
                        float px=sx-qls[q*3], py=sy-qls[q*3+1], pz=sz-qls[q*3+2];
                        if (px*px+py*py+pz*pz<=CUT2){
                            int sl=atomicAdd(&cnt,1);
                            eqb[sl]=q; eidxb[sl]=idx; posx[sl]=px; posy[sl]=py; posz[sl]=pz;
                        }
                    }
                }
            }
            __syncthreads();
            process(cnt);
        }
    }
    __syncthreads();

    for (int j=t; j<QB*CIN; j+=NTB){
        int q=j>>6, o=j&63, n=nq0+q;
        if (n<N) out[(size_t)n*CIN+o]=outacc[q*OSTR+o];
    }
}

extern "C" void kernel_launch(void* const* d_in, const int* in_sizes, int n_in,
                              void* d_out, int out_size, void* d_ws, size_t ws_size,
                              hipStream_t stream)
{
    const float* q_pts=(const float*)d_in[0];
    const float* s_pts=(const float*)d_in[1];
    const int*   inds =(const int*)d_in[2];
    const float* x    =(const float*)d_in[3];
    const float* W    =(const float*)d_in[4];
    const float* kpts =(const float*)d_in[5];
    float* outp=(float*)d_out;
    int N=in_sizes[0]/3;
    int M=in_sizes[1]/3;

    char* wsb=(char*)d_ws;
    float4* sp4=(float4*)wsb;
    unsigned short* Wt2=(unsigned short*)(wsb + (size_t)M*16);

    const size_t WT2B = (size_t)KP*8*64*8*2;            // 221184
    size_t offC = (size_t)M*16 + WT2B;                  // 16/256-aligned
    size_t newNeed = offC + 256 + (size_t)EMAX*16 + (size_t)EMAX*4 + (size_t)OMAX*4;

    if (ws_size >= newNeed){
        int*    ctrs =(int*)   (wsb + offC);
        float4* meta =(float4*)(wsb + offC + 256);
        int*    idxA =(int*)   (wsb + offC + 256 + (size_t)EMAX*16);
        int*    ovf  =(int*)   (wsb + offC + 256 + (size_t)EMAX*16 + (size_t)EMAX*4);

        int prepN = (M > KP*8*64) ? M : KP*8*64;
        hipLaunchKernelGGL(kp_prep, dim3((prepN+255)/256), dim3(256), 0, stream,
                           s_pts, W, sp4, Wt2, ctrs, M);
        int scanBlocks = (N*HN + PB - 1) / PB;
        hipLaunchKernelGGL(kp_scan2, dim3(scanBlocks), dim3(256), 0, stream,
                           q_pts, inds, sp4, outp, ctrs, meta, idxA, ovf, N, M);
        hipLaunchKernelGGL(kpconv_sp2, dim3(EMAX/TPB), dim3(256), 0, stream,
                           x, kpts, Wt2, meta, idxA, ctrs, ovf, inds, q_pts, sp4, W,
                           outp, N, M);
        return;
    }

    // fallback: previous best single-kernel path
    size_t need = (size_t)M*16 + WT2B;
    int use_ws = (ws_size >= need) ? 1 : 0;
    if (use_ws){
        hipLaunchKernelGGL(pack_spts, dim3((M+255)/256), dim3(256), 0, stream, s_pts, sp4, M);
        hipLaunchKernelGGL(pack_wt2, dim3((KP*8*64+255)/256), dim3(256), 0, stream, W, Wt2);
    }
    int nblocks = (N + QB - 1) / QB;
    hipLaunchKernelGGL(kpconv6, dim3(nblocks), dim3(NTB), 0, stream,
                       q_pts, s_pts, inds, x, W, kpts, sp4, Wt2, use_ws, outp, N, M);
}